// Round 2
// baseline (261.426 us; speedup 1.0000x reference)
//
#include <hip/hip_runtime.h>
#include <math.h>

#define BLOCK 256
// Layer cell counts (b=32, 3 anchors):
//  L0: 32*3*13*13 = 16224  -> 64 blocks   (13x13, anchors 6,7,8)
//  L1: 32*3*26*26 = 64896  -> 254 blocks  (26x26, anchors 3,4,5)
//  L2: 32*3*52*52 = 259584 -> 1014 blocks (52x52, anchors 0,1,2)
#define NB0 64
#define NB1 254
#define NB2 1014
#define NBLOCKS (NB0 + NB1 + NB2)

// anchors ordered [layer][a]: layer0 = ANCHORS[6,7,8], layer1 = [3,4,5], layer2 = [0,1,2]
__constant__ float c_anch[9][2] = {
    {116.f, 90.f}, {156.f, 198.f}, {373.f, 326.f},
    { 30.f, 61.f}, { 62.f,  45.f}, { 59.f, 119.f},
    { 10.f, 13.f}, { 16.f,  30.f}, { 33.f,  23.f}
};

// stable softplus: log(1+exp(x)) = max(x,0) + log(1+exp(-|x|))
__device__ __forceinline__ float softplusf(float x) {
    float ax = fabsf(x);
    return fmaxf(x, 0.f) + __logf(1.f + __expf(-ax));
}

__device__ __forceinline__ float sigmoidf(float x) {
    return __fdividef(1.f, 1.f + __expf(-x));
}

__global__ __launch_bounds__(BLOCK) void yolo_loss_main(
    const float* __restrict__ p0, const float* __restrict__ p1, const float* __restrict__ p2,
    const float* __restrict__ t0, const float* __restrict__ t1, const float* __restrict__ t2,
    const float* __restrict__ tgt, float* __restrict__ partials)
{
    int blk = blockIdx.x;
    const float* pred;
    const float* tru;
    int layer, g, cells, bbase;
    if (blk < NB0)            { layer = 0; pred = p0; tru = t0; g = 13; cells = 16224;  bbase = 0; }
    else if (blk < NB0 + NB1) { layer = 1; pred = p1; tru = t1; g = 26; cells = 64896;  bbase = NB0; }
    else                      { layer = 2; pred = p2; tru = t2; g = 52; cells = 259584; bbase = NB0 + NB1; }

    int idx = (blk - bbase) * BLOCK + threadIdx.x;
    float acc = 0.f;

    if (idx < cells) {
        int hw = g * g;
        int ij = idx % hw;
        int a  = (idx / hw) % 3;
        int b  = idx / (3 * hw);
        int i  = ij / g;
        int j  = ij - i * g;

        // raw[b][a][i][j][c] = y_pred[b][a*85+c][i][j]  (channel stride = hw)
        const float* pb = pred + (size_t)((b * 3 + a) * 85) * hw + ij;
        // y_true[b][a][i][j][c]  (channel-minor)
        const float* tb = tru + (size_t)((b * 3 + a) * hw + ij) * 85;

        float r0 = pb[0];
        float r1 = pb[hw];
        float r2 = pb[2 * hw];
        float r3 = pb[3 * hw];
        float r4 = pb[4 * hw];

        float y0 = tb[0], y1 = tb[1], y2 = tb[2], y3 = tb[3], mask = tb[4];

        float gf = (float)g, gx = (float)j, gy = (float)i;
        float aw = c_anch[layer * 3 + a][0];
        float ah = c_anch[layer * 3 + a][1];

        // ---- xy loss: bce(sigmoid(r), t) = softplus(r) - t*r ----
        float true_x = y0 * gf - gx;
        float true_y = y1 * gf - gy;
        float ls = 2.f - y2 * y3;   // loss_scale
        float lxy = (softplusf(r0) - true_x * r0) + (softplusf(r1) - true_y * r1);
        acc += mask * ls * lxy;

        // ---- wh loss ----
        float tw = __logf(y2 * (416.f / aw));
        float th = __logf(y3 * (416.f / ah));
        float dw = r2 - tw, dh = r3 - th;
        acc += mask * ls * 0.5f * (dw * dw + dh * dh);

        // ---- conf bce ----
        float cbce = softplusf(r4) - mask * r4;

        // ---- IoU vs 20 targets -> neg mask ----
        float sx = sigmoidf(r0);
        float sy = sigmoidf(r1);
        float bx = __fdividef(sx + gx, gf);
        float by = __fdividef(sy + gy, gf);
        float bw = __expf(r2) * aw * (1.f / 416.f);
        float bh = __expf(r3) * ah * (1.f / 416.f);
        float a1 = bw * bh;
        float b1minx = bx - 0.5f * bw, b1maxx = bx + 0.5f * bw;
        float b1miny = by - 0.5f * bh, b1maxy = by + 0.5f * bh;

        const float* tg = tgt + b * 20 * 5;
        float best = 0.f;
#pragma unroll 4
        for (int k = 0; k < 20; k++) {
            float tx  = tg[k * 5 + 0];
            float ty  = tg[k * 5 + 1];
            float tww = tg[k * 5 + 2];
            float thh = tg[k * 5 + 3];
            float iw = fminf(b1maxx, tx + 0.5f * tww) - fmaxf(b1minx, tx - 0.5f * tww);
            float ih = fminf(b1maxy, ty + 0.5f * thh) - fmaxf(b1miny, ty - 0.5f * thh);
            iw = fmaxf(iw, 0.f);
            ih = fmaxf(ih, 0.f);
            float inter = iw * ih;
            float iou = __fdividef(inter, a1 + tww * thh - inter);
            best = fmaxf(best, iou);
        }
        float neg = (best < 0.5f) ? 1.f : 0.f;
        acc += mask * cbce + (1.f - mask) * neg * cbce;

        // ---- class loss: sum over 80 classes of mask * (softplus(x) - t*x) ----
        float cls = 0.f;
#pragma unroll 8
        for (int c = 0; c < 80; c++) {
            float x = pb[(5 + c) * hw];
            float t = tb[5 + c];
            cls += softplusf(x) - t * x;
        }
        acc += mask * cls;
    }

    // ---- block reduction: wave shuffle then LDS ----
    for (int off = 32; off > 0; off >>= 1)
        acc += __shfl_down(acc, off, 64);
    __shared__ float sh[BLOCK / 64];
    if ((threadIdx.x & 63) == 0)
        sh[threadIdx.x >> 6] = acc;
    __syncthreads();
    if (threadIdx.x == 0) {
        float s = 0.f;
        for (int wv = 0; wv < BLOCK / 64; wv++) s += sh[wv];
        partials[blockIdx.x] = s;
    }
}

__global__ __launch_bounds__(BLOCK) void yolo_loss_reduce(
    const float* __restrict__ partials, float* __restrict__ out)
{
    float s = 0.f;
    for (int i = threadIdx.x; i < NBLOCKS; i += BLOCK)
        s += partials[i];
    for (int off = 32; off > 0; off >>= 1)
        s += __shfl_down(s, off, 64);
    __shared__ float sh[BLOCK / 64];
    if ((threadIdx.x & 63) == 0)
        sh[threadIdx.x >> 6] = s;
    __syncthreads();
    if (threadIdx.x == 0) {
        float tot = 0.f;
        for (int wv = 0; wv < BLOCK / 64; wv++) tot += sh[wv];
        out[0] = tot;
    }
}

extern "C" void kernel_launch(void* const* d_in, const int* in_sizes, int n_in,
                              void* d_out, int out_size, void* d_ws, size_t ws_size,
                              hipStream_t stream) {
    // setup_inputs() dict order is INTERLEAVED:
    //   d_in[0]=y_pred0, d_in[1]=y_true0, d_in[2]=y_pred1, d_in[3]=y_true1,
    //   d_in[4]=y_pred2, d_in[5]=y_true2, d_in[6]=target
    const float* p0  = (const float*)d_in[0];
    const float* t0  = (const float*)d_in[1];
    const float* p1  = (const float*)d_in[2];
    const float* t1  = (const float*)d_in[3];
    const float* p2  = (const float*)d_in[4];
    const float* t2  = (const float*)d_in[5];
    const float* tgt = (const float*)d_in[6];
    float* partials  = (float*)d_ws;   // NBLOCKS floats; every slot written each call

    yolo_loss_main<<<NBLOCKS, BLOCK, 0, stream>>>(p0, p1, p2, t0, t1, t2, tgt, partials);
    yolo_loss_reduce<<<1, BLOCK, 0, stream>>>(partials, (float*)d_out);
}